// Round 7
// baseline (100.558 us; speedup 1.0000x reference)
//
#include <hip/hip_runtime.h>
#include <hip/hip_bf16.h>
#include <math.h>

// Problem constants (reference: B=32, P=256, D=64, T=4096, SCALE=1)
#define Bb 32
#define Pp 256
#define Dd 64
#define Tt 4096

typedef unsigned short ushort_t;
typedef __attribute__((ext_vector_type(8))) short bf16x8;   // 8 bf16 = 4 VGPRs
typedef __attribute__((ext_vector_type(4))) float f32x4;

// Partials: 64 per (b,p), packed float2(lm = M + log2(ss), u = vv/ss).
#define TRIP_BYTES ((size_t)Bb * Pp * 64 * 8)    // 4,194,304
#define A_BF_BYTES ((size_t)Bb * Pp * Dd * 2)    // 1,048,576 (each of hi/lo)
#define B_BF_BYTES ((size_t)Tt * Dd * 2)         //   524,288 (each of hi/lo)
#define WS_NEED    (TRIP_BYTES + 2 * A_BF_BYTES + 2 * B_BF_BYTES)

// Log2-domain logits (R14/R16-validated): one v_exp_f32 per exp.
#define C2 (-0.7213475204444817f)   // -0.5 * log2(e)

__device__ __forceinline__ float fexp2(float x) {
  float r; asm("v_exp_f32 %0, %1" : "=v"(r) : "v"(x)); return r;
}
__device__ __forceinline__ float flog2(float x) {
  float r; asm("v_log_f32 %0, %1" : "=v"(r) : "v"(x)); return r;
}
__device__ __forceinline__ float frcp(float x) {
  float r; asm("v_rcp_f32 %0, %1" : "=v"(r) : "v"(x)); return r;
}

// ---- DPP row-local shuffle on the VALU pipe (R13-proven ctrl codes).
// quad_perm xor1 = 0xB1, quad_perm xor2 = 0x4E,
// row_half_mirror = 0x141 (cross-4 merge), row_mirror = 0x140 (cross-8).
template <int CTRL>
__device__ __forceinline__ float dppf(float x) {
  return __builtin_bit_cast(float,
      __builtin_amdgcn_update_dpp(0, __builtin_bit_cast(int, x), CTRL, 0xF, 0xF, true));
}

// R9-proven split-bf16 6-MFMA product (drops al*bl, ~2^-17 rel err)
__device__ __forceinline__ f32x4 mfma6(bf16x8 ah0, bf16x8 ah1, bf16x8 al0, bf16x8 al1,
                                       bf16x8 bh0, bf16x8 bh1, bf16x8 bl0, bf16x8 bl1) {
  f32x4 a = (f32x4)0.f;
  a = __builtin_amdgcn_mfma_f32_16x16x32_bf16(ah0, bh0, a, 0, 0, 0);
  a = __builtin_amdgcn_mfma_f32_16x16x32_bf16(ah1, bh1, a, 0, 0, 0);
  a = __builtin_amdgcn_mfma_f32_16x16x32_bf16(ah0, bl0, a, 0, 0, 0);
  a = __builtin_amdgcn_mfma_f32_16x16x32_bf16(al0, bh0, a, 0, 0, 0);
  a = __builtin_amdgcn_mfma_f32_16x16x32_bf16(ah1, bl1, a, 0, 0, 0);
  a = __builtin_amdgcn_mfma_f32_16x16x32_bf16(al1, bh1, a, 0, 0, 0);
  return a;
}

// =============== Phase 0: split-bf16 conversion of A and B ==================
__global__ __launch_bounds__(256) void k_conv(const float* __restrict__ data,
                                              const float* __restrict__ Wt,
                                              ushort_t* __restrict__ Ah, ushort_t* __restrict__ Al,
                                              ushort_t* __restrict__ Bh, ushort_t* __restrict__ Bl) {
  const int i  = blockIdx.x * 256 + threadIdx.x;
  const int NA = Bb * Pp * Dd;    // 524288
  const float x = (i < NA) ? data[i] : Wt[i - NA];
  const __hip_bfloat16 h = __float2bfloat16(x);
  const float hf = __bfloat162float(h);
  const __hip_bfloat16 l = __float2bfloat16(x - hf);
  if (i < NA) { Ah[i] = *(const ushort_t*)&h; Al[i] = *(const ushort_t*)&l; }
  else        { const int j = i - NA;
                Bh[j] = *(const ushort_t*)&h; Bl[j] = *(const ushort_t*)&l; }
}

// ==================== Phase 1: one-pass fused prefix-softmax ================
// R19: profile discovery — the harness re-poison (fillBufferAligned, 256 MiB,
// ~42us) is INSIDE the timed window; addressable budget is our ~56us of
// kernels+gaps. k_main is stall-bound, not issue-bound (measured ~6000
// SIMD-cyc/sg vs ~1000 issue-cyc; R16 showed more waves doesn't help, R18
// showed fewer ops barely helps). Fix: intra-wave ILP. Each iteration now
// processes TWO independent 16-row blocks (X: p0..p0+15, Y: p0+16..p0+31)
// sharing the B-frags — 8 iterations instead of 16. X and Y are independent
// through MFMA/scores/scan/softmax/store (R chains them exactly like two
// sequential sgs: baseY = R + totX + preY; same summation order), so the
// scheduler can fill X's dependency stalls with Y's instructions and vice
// versa. Per-iteration loop/R overhead also halves. A-prefetch dropped (live
// regs: B 64 + aX/aY 32 + cc 32 + misc ~30 ≈ 160 < 256 cap at (256,2);
// one L1-hot load stall per iteration is cheap).
// Numerics: log2-domain logits, M-first exact-max softmax, float2(lm,u)
// partials — all R18-proven, unchanged per 16-row block.
__global__ __launch_bounds__(256, 2) void k_main(const ushort_t* __restrict__ Ah,
                                                 const ushort_t* __restrict__ Al,
                                                 const ushort_t* __restrict__ Bh,
                                                 const ushort_t* __restrict__ Bl,
                                                 const float* __restrict__ targets,
                                                 float2* __restrict__ trips) {
  const int tid  = threadIdx.x;
  const int wid  = tid >> 6;
  const int lane = tid & 63;
  const int quad = lane >> 4;
  const int l16  = lane & 15;
  const int b     = blockIdx.x >> 4;
  const int strip = blockIdx.x & 15;
  const int t0    = strip * 256;
  const int wstrip = strip * 4 + wid;           // 0..63 (this wave's t-subset id)

  // ---- B fragments for this wave's 64 t-columns: VGPR-resident throughout.
  bf16x8 vbh0[4], vbh1[4], vbl0[4], vbl1[4];
#pragma unroll
  for (int nt = 0; nt < 4; ++nt) {
    const size_t boff = (size_t)(t0 + wid * 64 + nt * 16 + l16) * Dd + quad * 8;
    vbh0[nt] = *(const bf16x8*)(Bh + boff);
    vbh1[nt] = *(const bf16x8*)(Bh + boff + 32);
    vbl0[nt] = *(const bf16x8*)(Bl + boff);
    vbl1[nt] = *(const bf16x8*)(Bl + boff + 32);
  }

  const ushort_t* arow_base = Ah + (size_t)b * Pp * Dd;
  const ushort_t* alow_base = Al + (size_t)b * Pp * Dd;
  const float* tgt          = targets + b * Pp;
  float2* __restrict__ trb  = trips + (size_t)b * Pp * 64;

  float R[4];                                   // per-column running prefix (log2)
#pragma unroll
  for (int nt = 0; nt < 4; ++nt) R[nt] = 0.f;

#pragma unroll 1
  for (int it = 0; it < 8; ++it) {
    const int p0 = it * 32;

    // ---- A fragments for both 16-row blocks (L1-hot; shared by the block's
    // 4 waves). Issued together so both MFMA streams can start.
    const size_t aoffX = (size_t)(p0 + l16) * Dd + quad * 8;
    const bf16x8 xah0 = *(const bf16x8*)(arow_base + aoffX);
    const bf16x8 xah1 = *(const bf16x8*)(arow_base + aoffX + 32);
    const bf16x8 xal0 = *(const bf16x8*)(alow_base + aoffX);
    const bf16x8 xal1 = *(const bf16x8*)(alow_base + aoffX + 32);
    const size_t aoffY = aoffX + (size_t)16 * Dd;
    const bf16x8 yah0 = *(const bf16x8*)(arow_base + aoffY);
    const bf16x8 yah1 = *(const bf16x8*)(arow_base + aoffY + 32);
    const bf16x8 yal0 = *(const bf16x8*)(alow_base + aoffY);
    const bf16x8 yal1 = *(const bf16x8*)(alow_base + aoffY + 32);
    const float4 tqX  = *(const float4*)(tgt + p0 + quad * 4);
    const float4 tqY  = *(const float4*)(tgt + p0 + 16 + quad * 4);

    // ---- two independent MFMA streams (share B)
    f32x4 aX[4], aY[4];
#pragma unroll
    for (int nt = 0; nt < 4; ++nt)
      aX[nt] = mfma6(xah0, xah1, xal0, xal1, vbh0[nt], vbh1[nt], vbl0[nt], vbl1[nt]);
#pragma unroll
    for (int nt = 0; nt < 4; ++nt)
      aY[nt] = mfma6(yah0, yah1, yal0, yal1, vbh0[nt], vbh1[nt], vbl0[nt], vbl1[nt]);

    // ---- scores + quad-exclusive prefix, X block then Y block (R chaining:
    // baseY includes X's full 16-row colsum -> identical summation order to
    // two sequential sgs of the R18 kernel)
    float ccX[4][4], ccY[4][4], totX[4];
#pragma unroll
    for (int nt = 0; nt < 4; ++nt) {
      float sc0, sc1, sc2, sc3;
      { const float e = tqX.x - aX[nt][0]; sc0 = C2 * e * e; }
      { const float e = tqX.y - aX[nt][1]; sc1 = C2 * e * e; }
      { const float e = tqX.z - aX[nt][2]; sc2 = C2 * e * e; }
      { const float e = tqX.w - aX[nt][3]; sc3 = C2 * e * e; }
      const float colsum = (sc0 + sc1) + (sc2 + sc3);
      const float x1 = __shfl_xor(colsum, 16, 64);
      const float x2 = __shfl_xor(colsum, 32, 64);
      const float x3 = __shfl_xor(x1, 32, 64);
      const float pre = (quad == 0) ? 0.f
                      : (quad == 1) ? x1
                      : (quad == 2) ? (x2 + x3)
                                    : (x1 + x2 + x3);
      const float base = R[nt] + pre;
      ccX[nt][0] = base;
      ccX[nt][1] = base + sc0;
      ccX[nt][2] = ccX[nt][1] + sc1;
      ccX[nt][3] = ccX[nt][2] + sc2;
      totX[nt] = ((colsum + x1) + (x2 + x3));
    }
#pragma unroll
    for (int nt = 0; nt < 4; ++nt) {
      float sc0, sc1, sc2, sc3;
      { const float e = tqY.x - aY[nt][0]; sc0 = C2 * e * e; }
      { const float e = tqY.y - aY[nt][1]; sc1 = C2 * e * e; }
      { const float e = tqY.z - aY[nt][2]; sc2 = C2 * e * e; }
      { const float e = tqY.w - aY[nt][3]; sc3 = C2 * e * e; }
      const float colsum = (sc0 + sc1) + (sc2 + sc3);
      const float x1 = __shfl_xor(colsum, 16, 64);
      const float x2 = __shfl_xor(colsum, 32, 64);
      const float x3 = __shfl_xor(x1, 32, 64);
      const float pre = (quad == 0) ? 0.f
                      : (quad == 1) ? x1
                      : (quad == 2) ? (x2 + x3)
                                    : (x1 + x2 + x3);
      const float base = (R[nt] + totX[nt]) + pre;
      ccY[nt][0] = base;
      ccY[nt][1] = base + sc0;
      ccY[nt][2] = ccY[nt][1] + sc1;
      ccY[nt][3] = ccY[nt][2] + sc2;
      R[nt] += totX[nt] + ((colsum + x1) + (x2 + x3));
    }

    // ---- M-first softmax, X block (exact max -> single exp2 per column)
    {
      float M[4];
#pragma unroll
      for (int r = 0; r < 4; ++r)
        M[r] = fmaxf(fmaxf(ccX[0][r], ccX[1][r]), fmaxf(ccX[2][r], ccX[3][r]));
#pragma unroll
      for (int r = 0; r < 4; ++r) M[r] = fmaxf(M[r], dppf<0xB1>(M[r]));
#pragma unroll
      for (int r = 0; r < 4; ++r) M[r] = fmaxf(M[r], dppf<0x4E>(M[r]));
#pragma unroll
      for (int r = 0; r < 4; ++r) M[r] = fmaxf(M[r], dppf<0x141>(M[r]));
#pragma unroll
      for (int r = 0; r < 4; ++r) M[r] = fmaxf(M[r], dppf<0x140>(M[r]));

      float ss[4], vv[4];
#pragma unroll
      for (int r = 0; r < 4; ++r) {
        float s = 0.f, v = 0.f;
#pragma unroll
        for (int nt = 0; nt < 4; ++nt) {
          const float e = fexp2(ccX[nt][r] - M[r]);
          s += e;
          v = fmaf(e, aX[nt][r], v);
        }
        ss[r] = s; vv[r] = v;
      }
#pragma unroll
      for (int r = 0; r < 4; ++r) { ss[r] += dppf<0xB1>(ss[r]);  vv[r] += dppf<0xB1>(vv[r]); }
#pragma unroll
      for (int r = 0; r < 4; ++r) { ss[r] += dppf<0x4E>(ss[r]);  vv[r] += dppf<0x4E>(vv[r]); }
#pragma unroll
      for (int r = 0; r < 4; ++r) { ss[r] += dppf<0x141>(ss[r]); vv[r] += dppf<0x141>(vv[r]); }
#pragma unroll
      for (int r = 0; r < 4; ++r) { ss[r] += dppf<0x140>(ss[r]); vv[r] += dppf<0x140>(vv[r]); }

      if (l16 == 0) {
#pragma unroll
        for (int r = 0; r < 4; ++r) {
          const float lm = M[r] + flog2(ss[r]);   // ss >= 1 -> log2 safe
          const float u  = vv[r] * frcp(ss[r]);
          const int p = p0 + quad * 4 + r;
          trb[p * 64 + wstrip] = make_float2(lm, u);
        }
      }
    }

    // ---- M-first softmax, Y block
    {
      float M[4];
#pragma unroll
      for (int r = 0; r < 4; ++r)
        M[r] = fmaxf(fmaxf(ccY[0][r], ccY[1][r]), fmaxf(ccY[2][r], ccY[3][r]));
#pragma unroll
      for (int r = 0; r < 4; ++r) M[r] = fmaxf(M[r], dppf<0xB1>(M[r]));
#pragma unroll
      for (int r = 0; r < 4; ++r) M[r] = fmaxf(M[r], dppf<0x4E>(M[r]));
#pragma unroll
      for (int r = 0; r < 4; ++r) M[r] = fmaxf(M[r], dppf<0x141>(M[r]));
#pragma unroll
      for (int r = 0; r < 4; ++r) M[r] = fmaxf(M[r], dppf<0x140>(M[r]));

      float ss[4], vv[4];
#pragma unroll
      for (int r = 0; r < 4; ++r) {
        float s = 0.f, v = 0.f;
#pragma unroll
        for (int nt = 0; nt < 4; ++nt) {
          const float e = fexp2(ccY[nt][r] - M[r]);
          s += e;
          v = fmaf(e, aY[nt][r], v);
        }
        ss[r] = s; vv[r] = v;
      }
#pragma unroll
      for (int r = 0; r < 4; ++r) { ss[r] += dppf<0xB1>(ss[r]);  vv[r] += dppf<0xB1>(vv[r]); }
#pragma unroll
      for (int r = 0; r < 4; ++r) { ss[r] += dppf<0x4E>(ss[r]);  vv[r] += dppf<0x4E>(vv[r]); }
#pragma unroll
      for (int r = 0; r < 4; ++r) { ss[r] += dppf<0x141>(ss[r]); vv[r] += dppf<0x141>(vv[r]); }
#pragma unroll
      for (int r = 0; r < 4; ++r) { ss[r] += dppf<0x140>(ss[r]); vv[r] += dppf<0x140>(vv[r]); }

      if (l16 == 0) {
#pragma unroll
        for (int r = 0; r < 4; ++r) {
          const float lm = M[r] + flog2(ss[r]);
          const float u  = vv[r] * frcp(ss[r]);
          const int p = p0 + 16 + quad * 4 + r;
          trb[p * 64 + wstrip] = make_float2(lm, u);
        }
      }
    }
  }
}

// ==================== Phase 2: cross-strip merge (separate, parallel) =======
__global__ __launch_bounds__(256) void k_merge(const float2* __restrict__ ws,
                                               float* __restrict__ out) {
  const int gt   = blockIdx.x * 256 + threadIdx.x;
  const int bp   = gt >> 6;
  const int lane = gt & 63;
  const float2 e = ws[(size_t)bp * 64 + lane];
  float M = e.x;
#pragma unroll
  for (int off = 32; off; off >>= 1) M = fmaxf(M, __shfl_xor(M, off, 64));
  const float f = fexp2(e.x - M);
  float S = f, V = f * e.y;
#pragma unroll
  for (int off = 32; off; off >>= 1) {
    S += __shfl_xor(S, off, 64);
    V += __shfl_xor(V, off, 64);
  }
  if (lane == 0) out[bp] = V / S;
}

// ============== Fallback (tiny ws): fused R1 structure + merge ==============
__global__ __launch_bounds__(256) void k_scan_fused(const float* __restrict__ data,
                                                    const float* __restrict__ targets,
                                                    const float* __restrict__ task_pool,
                                                    float2* __restrict__ ws) {
  const int b     = blockIdx.x >> 4;
  const int wid   = threadIdx.x >> 6;
  const int lane  = threadIdx.x & 63;
  const int chunk = ((blockIdx.x & 15) << 2) | wid;
  const int t     = (chunk << 6) | lane;
  float w[Dd];
#pragma unroll
  for (int d = 0; d < Dd; d += 4) {
    const float4 r = *(const float4*)(task_pool + (size_t)t * Dd + d);
    w[d] = r.x; w[d + 1] = r.y; w[d + 2] = r.z; w[d + 3] = r.w;
  }
  const float* drow = data + (size_t)b * (Pp * Dd);
  const float* tgt  = targets + b * Pp;
  float2* wsb       = ws + (size_t)b * (Pp * 64);
  float c = 0.f;
  for (int p = 0; p < Pp; ++p) {
    float a0 = 0.f, a1 = 0.f, a2 = 0.f, a3 = 0.f;
    const float* r = drow + p * Dd;
#pragma unroll
    for (int d = 0; d < Dd; d += 4) {
      a0 = fmaf(r[d], w[d], a0);         a1 = fmaf(r[d + 1], w[d + 1], a1);
      a2 = fmaf(r[d + 2], w[d + 2], a2); a3 = fmaf(r[d + 3], w[d + 3], a3);
    }
    const float pred = (a0 + a1) + (a2 + a3);
    float m = c;
#pragma unroll
    for (int off = 32; off; off >>= 1) m = fmaxf(m, __shfl_xor(m, off, 64));
    const float e = fexp2(c - m);
    float s = e, v = e * pred;
#pragma unroll
    for (int off = 32; off; off >>= 1) {
      s += __shfl_xor(s, off, 64);
      v += __shfl_xor(v, off, 64);
    }
    if (lane == 0) wsb[p * 64 + chunk] = make_float2(m + flog2(s), v * frcp(s));
    const float err = tgt[p] - pred;
    c = fmaf(C2 * err, err, c);
  }
}

extern "C" void kernel_launch(void* const* d_in, const int* in_sizes, int n_in,
                              void* d_out, int out_size, void* d_ws, size_t ws_size,
                              hipStream_t stream) {
  const float* data      = (const float*)d_in[0];
  const float* targets   = (const float*)d_in[1];
  const float* task_pool = (const float*)d_in[2];
  float* out = (float*)d_out;

  if (ws_size >= WS_NEED) {
    float2*   trips = (float2*)d_ws;
    char*     cb    = (char*)d_ws + TRIP_BYTES;
    ushort_t* Ah    = (ushort_t*)cb;
    ushort_t* Al    = (ushort_t*)(cb + A_BF_BYTES);
    ushort_t* Bh    = (ushort_t*)(cb + 2 * A_BF_BYTES);
    ushort_t* Bl    = (ushort_t*)(cb + 2 * A_BF_BYTES + B_BF_BYTES);
    k_conv <<<dim3((Bb * Pp * Dd + Tt * Dd) / 256), dim3(256), 0, stream>>>(
        data, task_pool, Ah, Al, Bh, Bl);
    k_main <<<dim3(Bb * 16), dim3(256), 0, stream>>>(Ah, Al, Bh, Bl, targets, trips);
    k_merge<<<dim3((Bb * Pp * 64) / 256), dim3(256), 0, stream>>>(trips, out);
  } else {
    float2* trips = (float2*)d_ws;   // 4.2 MB
    k_scan_fused<<<dim3(512), dim3(256), 0, stream>>>(data, targets, task_pool, trips);
    k_merge<<<dim3((Bb * Pp * 64) / 256), dim3(256), 0, stream>>>(trips, out);
  }
}

// Round 8
// 99.538 us; speedup vs baseline: 1.0103x; 1.0103x over previous
//
#include <hip/hip_runtime.h>
#include <hip/hip_bf16.h>
#include <math.h>

// Problem constants (reference: B=32, P=256, D=64, T=4096, SCALE=1)
#define Bb 32
#define Pp 256
#define Dd 64
#define Tt 4096

typedef unsigned short ushort_t;
typedef __attribute__((ext_vector_type(8))) short bf16x8;   // 8 bf16 = 4 VGPRs
typedef __attribute__((ext_vector_type(4))) float f32x4;

// Partials: 64 per (b,p), packed float2(lm = M + log2(ss), u = vv/ss).
#define TRIP_BYTES ((size_t)Bb * Pp * 64 * 8)    // 4,194,304
#define A_BF_BYTES ((size_t)Bb * Pp * Dd * 2)    // 1,048,576 (each of hi/lo)
#define B_BF_BYTES ((size_t)Tt * Dd * 2)         //   524,288 (each of hi/lo)
#define WS_NEED    (TRIP_BYTES + 2 * A_BF_BYTES + 2 * B_BF_BYTES)

// Log2-domain logits (R14/R16-validated): one v_exp_f32 per exp.
#define C2 (-0.7213475204444817f)   // -0.5 * log2(e)

__device__ __forceinline__ float fexp2(float x) {
  float r; asm("v_exp_f32 %0, %1" : "=v"(r) : "v"(x)); return r;
}
__device__ __forceinline__ float flog2(float x) {
  float r; asm("v_log_f32 %0, %1" : "=v"(r) : "v"(x)); return r;
}
__device__ __forceinline__ float frcp(float x) {
  float r; asm("v_rcp_f32 %0, %1" : "=v"(r) : "v"(x)); return r;
}

// ---- DPP row-local shuffle on the VALU pipe (R13-proven ctrl codes).
// quad_perm xor1 = 0xB1, quad_perm xor2 = 0x4E,
// row_half_mirror = 0x141 (cross-4 merge), row_mirror = 0x140 (cross-8).
template <int CTRL>
__device__ __forceinline__ float dppf(float x) {
  return __builtin_bit_cast(float,
      __builtin_amdgcn_update_dpp(0, __builtin_bit_cast(int, x), CTRL, 0xF, 0xF, true));
}

// R9-proven split-bf16 6-MFMA product (drops al*bl, ~2^-17 rel err)
__device__ __forceinline__ f32x4 mfma6(bf16x8 ah0, bf16x8 ah1, bf16x8 al0, bf16x8 al1,
                                       bf16x8 bh0, bf16x8 bh1, bf16x8 bl0, bf16x8 bl1) {
  f32x4 a = (f32x4)0.f;
  a = __builtin_amdgcn_mfma_f32_16x16x32_bf16(ah0, bh0, a, 0, 0, 0);
  a = __builtin_amdgcn_mfma_f32_16x16x32_bf16(ah1, bh1, a, 0, 0, 0);
  a = __builtin_amdgcn_mfma_f32_16x16x32_bf16(ah0, bl0, a, 0, 0, 0);
  a = __builtin_amdgcn_mfma_f32_16x16x32_bf16(al0, bh0, a, 0, 0, 0);
  a = __builtin_amdgcn_mfma_f32_16x16x32_bf16(ah1, bl1, a, 0, 0, 0);
  a = __builtin_amdgcn_mfma_f32_16x16x32_bf16(al1, bh1, a, 0, 0, 0);
  return a;
}

// =============== Phase 0: split-bf16 conversion of A and B ==================
__global__ __launch_bounds__(256) void k_conv(const float* __restrict__ data,
                                              const float* __restrict__ Wt,
                                              ushort_t* __restrict__ Ah, ushort_t* __restrict__ Al,
                                              ushort_t* __restrict__ Bh, ushort_t* __restrict__ Bl) {
  const int i  = blockIdx.x * 256 + threadIdx.x;
  const int NA = Bb * Pp * Dd;    // 524288
  const float x = (i < NA) ? data[i] : Wt[i - NA];
  const __hip_bfloat16 h = __float2bfloat16(x);
  const float hf = __bfloat162float(h);
  const __hip_bfloat16 l = __float2bfloat16(x - hf);
  if (i < NA) { Ah[i] = *(const ushort_t*)&h; Al[i] = *(const ushort_t*)&l; }
  else        { const int j = i - NA;
                Bh[j] = *(const ushort_t*)&h; Bl[j] = *(const ushort_t*)&l; }
}

// ==================== Phase 1: one-pass fused prefix-softmax ================
// R20: R19's dual-row ILP reverted (45.6us > R18's ~40; both softmax tails
// still serial + A-prefetch loss). This round: explicit 1-deep SOFTWARE
// PIPELINE inside the unroll-1 loop. Each sg splits into:
//   stage1 (R-independent): A-load -> 24 MFMA -> scores -> scan shuffles;
//     carries av[4][4], ccp[4][4] (= pre + cumsum(sc), excl. R), tot[4].
//   stage2 (R-dependent spine): cc = R + ccp -> M-butterfly -> exp2 ->
//     ss/vv butterflies -> float2(lm,u) store.
// Iteration sg issues stage1(sg+1) FIRST, then stage2(sg): sg+1's MFMA
// issue, A-load latency and scan DS latency all hide under sg's ~400-cyc
// softmax chain (they are fully independent). Carried state ~+36 VGPR over
// R18's 84 -> well under the 256 cap at (256,2); NOT using the 128-cap that
// caused R14/R15 spills.
// Numerics: R18-proven (log2 domain, M-first exact-max softmax, lm/u
// partials); one benign reassociation (R+(pre+sc0) vs (R+pre)+sc0).
__device__ __forceinline__ void stage1(
    const ushort_t* __restrict__ arow_base, const ushort_t* __restrict__ alow_base,
    size_t aoff, float4 tq, int quad,
    const bf16x8 (&vbh0)[4], const bf16x8 (&vbh1)[4],
    const bf16x8 (&vbl0)[4], const bf16x8 (&vbl1)[4],
    float (&av)[4][4], float (&ccp)[4][4], float (&tot)[4]) {
  const bf16x8 ah0 = *(const bf16x8*)(arow_base + aoff);
  const bf16x8 ah1 = *(const bf16x8*)(arow_base + aoff + 32);
  const bf16x8 al0 = *(const bf16x8*)(alow_base + aoff);
  const bf16x8 al1 = *(const bf16x8*)(alow_base + aoff + 32);
#pragma unroll
  for (int nt = 0; nt < 4; ++nt) {
    const f32x4 a = mfma6(ah0, ah1, al0, al1,
                          vbh0[nt], vbh1[nt], vbl0[nt], vbl1[nt]);
    float sc0, sc1, sc2, sc3;
    { const float e = tq.x - a[0]; sc0 = C2 * e * e; }
    { const float e = tq.y - a[1]; sc1 = C2 * e * e; }
    { const float e = tq.z - a[2]; sc2 = C2 * e * e; }
    { const float e = tq.w - a[3]; sc3 = C2 * e * e; }

    // quad-exclusive prefix of column sums (R11-proven; cross-row -> DS)
    const float colsum = (sc0 + sc1) + (sc2 + sc3);
    const float x1 = __shfl_xor(colsum, 16, 64);
    const float x2 = __shfl_xor(colsum, 32, 64);
    const float x3 = __shfl_xor(x1, 32, 64);
    const float pre = (quad == 0) ? 0.f
                    : (quad == 1) ? x1
                    : (quad == 2) ? (x2 + x3)
                                  : (x1 + x2 + x3);
    ccp[nt][0] = pre;
    ccp[nt][1] = pre + sc0;
    ccp[nt][2] = ccp[nt][1] + sc1;
    ccp[nt][3] = ccp[nt][2] + sc2;
    av[nt][0] = a[0]; av[nt][1] = a[1]; av[nt][2] = a[2]; av[nt][3] = a[3];
    tot[nt] = ((colsum + x1) + (x2 + x3));
  }
}

__device__ __forceinline__ void stage2(
    int p0, int quad, int l16, int wstrip,
    const float (&av)[4][4], const float (&ccp)[4][4], const float (&R)[4],
    float2* __restrict__ trb) {
  float cc[4][4];
#pragma unroll
  for (int nt = 0; nt < 4; ++nt)
#pragma unroll
    for (int r = 0; r < 4; ++r) cc[nt][r] = R[nt] + ccp[nt][r];

  // M-first softmax: exact max over 64 t (in-lane 4 + DPP butterfly)
  float M[4];
#pragma unroll
  for (int r = 0; r < 4; ++r)
    M[r] = fmaxf(fmaxf(cc[0][r], cc[1][r]), fmaxf(cc[2][r], cc[3][r]));
#pragma unroll
  for (int r = 0; r < 4; ++r) M[r] = fmaxf(M[r], dppf<0xB1>(M[r]));   // xor1
#pragma unroll
  for (int r = 0; r < 4; ++r) M[r] = fmaxf(M[r], dppf<0x4E>(M[r]));   // xor2
#pragma unroll
  for (int r = 0; r < 4; ++r) M[r] = fmaxf(M[r], dppf<0x141>(M[r]));  // cross-4
#pragma unroll
  for (int r = 0; r < 4; ++r) M[r] = fmaxf(M[r], dppf<0x140>(M[r]));  // cross-8

  // single exp2 per column against the exact max (argmax term == 1)
  float ss[4], vv[4];
#pragma unroll
  for (int r = 0; r < 4; ++r) {
    float s = 0.f, v = 0.f;
#pragma unroll
    for (int nt = 0; nt < 4; ++nt) {
      const float e = fexp2(cc[nt][r] - M[r]);
      s += e;
      v = fmaf(e, av[nt][r], v);
    }
    ss[r] = s; vv[r] = v;
  }

#pragma unroll
  for (int r = 0; r < 4; ++r) { ss[r] += dppf<0xB1>(ss[r]);  vv[r] += dppf<0xB1>(vv[r]); }
#pragma unroll
  for (int r = 0; r < 4; ++r) { ss[r] += dppf<0x4E>(ss[r]);  vv[r] += dppf<0x4E>(vv[r]); }
#pragma unroll
  for (int r = 0; r < 4; ++r) { ss[r] += dppf<0x141>(ss[r]); vv[r] += dppf<0x141>(vv[r]); }
#pragma unroll
  for (int r = 0; r < 4; ++r) { ss[r] += dppf<0x140>(ss[r]); vv[r] += dppf<0x140>(vv[r]); }

  if (l16 == 0) {
#pragma unroll
    for (int r = 0; r < 4; ++r) {
      const float lm = M[r] + flog2(ss[r]);   // ss >= 1 -> log2 safe
      const float u  = vv[r] * frcp(ss[r]);
      const int p = p0 + quad * 4 + r;
      trb[p * 64 + wstrip] = make_float2(lm, u);
    }
  }
}

__global__ __launch_bounds__(256, 2) void k_main(const ushort_t* __restrict__ Ah,
                                                 const ushort_t* __restrict__ Al,
                                                 const ushort_t* __restrict__ Bh,
                                                 const ushort_t* __restrict__ Bl,
                                                 const float* __restrict__ targets,
                                                 float2* __restrict__ trips) {
  const int tid  = threadIdx.x;
  const int wid  = tid >> 6;
  const int lane = tid & 63;
  const int quad = lane >> 4;
  const int l16  = lane & 15;
  const int b     = blockIdx.x >> 4;
  const int strip = blockIdx.x & 15;
  const int t0    = strip * 256;
  const int wstrip = strip * 4 + wid;           // 0..63 (this wave's t-subset id)

  // ---- B fragments for this wave's 64 t-columns: VGPR-resident throughout.
  bf16x8 vbh0[4], vbh1[4], vbl0[4], vbl1[4];
#pragma unroll
  for (int nt = 0; nt < 4; ++nt) {
    const size_t boff = (size_t)(t0 + wid * 64 + nt * 16 + l16) * Dd + quad * 8;
    vbh0[nt] = *(const bf16x8*)(Bh + boff);
    vbh1[nt] = *(const bf16x8*)(Bh + boff + 32);
    vbl0[nt] = *(const bf16x8*)(Bl + boff);
    vbl1[nt] = *(const bf16x8*)(Bl + boff + 32);
  }

  const ushort_t* arow_base = Ah + (size_t)b * Pp * Dd;
  const ushort_t* alow_base = Al + (size_t)b * Pp * Dd;
  const float* tgt          = targets + b * Pp;
  float2* __restrict__ trb  = trips + (size_t)b * Pp * 64;

  float R[4];                                   // per-column running prefix (log2)
#pragma unroll
  for (int nt = 0; nt < 4; ++nt) R[nt] = 0.f;

  // ---- pipeline prologue: stage1 for sg=0
  float avC[4][4], ccpC[4][4], totC[4];
  {
    const size_t aoff0 = (size_t)l16 * Dd + quad * 8;
    const float4 tq0 = *(const float4*)(tgt + quad * 4);
    stage1(arow_base, alow_base, aoff0, tq0, quad,
           vbh0, vbh1, vbl0, vbl1, avC, ccpC, totC);
  }

#pragma unroll 1
  for (int sg = 0; sg < 15; ++sg) {
    // ---- stage1(sg+1): issued FIRST so its A-load / MFMA / DS-shuffle
    // latencies overlap stage2(sg)'s serial softmax spine.
    float avN[4][4], ccpN[4][4], totN[4];
    const int pn = (sg + 1) * 16;
    const size_t an = (size_t)(pn + l16) * Dd + quad * 8;
    const float4 tqN = *(const float4*)(tgt + pn + quad * 4);
    stage1(arow_base, alow_base, an, tqN, quad,
           vbh0, vbh1, vbl0, vbl1, avN, ccpN, totN);

    // ---- stage2(sg): R-dependent spine
    stage2(sg * 16, quad, l16, wstrip, avC, ccpC, R, trb);

    // ---- rotate pipeline
#pragma unroll
    for (int nt = 0; nt < 4; ++nt) {
      R[nt] += totC[nt];
#pragma unroll
      for (int r = 0; r < 4; ++r) { avC[nt][r] = avN[nt][r]; ccpC[nt][r] = ccpN[nt][r]; }
      totC[nt] = totN[nt];
    }
  }

  // ---- pipeline epilogue: stage2 for sg=15
  stage2(240, quad, l16, wstrip, avC, ccpC, R, trb);
}

// ==================== Phase 2: cross-strip merge (separate, parallel) =======
__global__ __launch_bounds__(256) void k_merge(const float2* __restrict__ ws,
                                               float* __restrict__ out) {
  const int gt   = blockIdx.x * 256 + threadIdx.x;
  const int bp   = gt >> 6;
  const int lane = gt & 63;
  const float2 e = ws[(size_t)bp * 64 + lane];
  float M = e.x;
#pragma unroll
  for (int off = 32; off; off >>= 1) M = fmaxf(M, __shfl_xor(M, off, 64));
  const float f = fexp2(e.x - M);
  float S = f, V = f * e.y;
#pragma unroll
  for (int off = 32; off; off >>= 1) {
    S += __shfl_xor(S, off, 64);
    V += __shfl_xor(V, off, 64);
  }
  if (lane == 0) out[bp] = V / S;
}

// ============== Fallback (tiny ws): fused R1 structure + merge ==============
__global__ __launch_bounds__(256) void k_scan_fused(const float* __restrict__ data,
                                                    const float* __restrict__ targets,
                                                    const float* __restrict__ task_pool,
                                                    float2* __restrict__ ws) {
  const int b     = blockIdx.x >> 4;
  const int wid   = threadIdx.x >> 6;
  const int lane  = threadIdx.x & 63;
  const int chunk = ((blockIdx.x & 15) << 2) | wid;
  const int t     = (chunk << 6) | lane;
  float w[Dd];
#pragma unroll
  for (int d = 0; d < Dd; d += 4) {
    const float4 r = *(const float4*)(task_pool + (size_t)t * Dd + d);
    w[d] = r.x; w[d + 1] = r.y; w[d + 2] = r.z; w[d + 3] = r.w;
  }
  const float* drow = data + (size_t)b * (Pp * Dd);
  const float* tgt  = targets + b * Pp;
  float2* wsb       = ws + (size_t)b * (Pp * 64);
  float c = 0.f;
  for (int p = 0; p < Pp; ++p) {
    float a0 = 0.f, a1 = 0.f, a2 = 0.f, a3 = 0.f;
    const float* r = drow + p * Dd;
#pragma unroll
    for (int d = 0; d < Dd; d += 4) {
      a0 = fmaf(r[d], w[d], a0);         a1 = fmaf(r[d + 1], w[d + 1], a1);
      a2 = fmaf(r[d + 2], w[d + 2], a2); a3 = fmaf(r[d + 3], w[d + 3], a3);
    }
    const float pred = (a0 + a1) + (a2 + a3);
    float m = c;
#pragma unroll
    for (int off = 32; off; off >>= 1) m = fmaxf(m, __shfl_xor(m, off, 64));
    const float e = fexp2(c - m);
    float s = e, v = e * pred;
#pragma unroll
    for (int off = 32; off; off >>= 1) {
      s += __shfl_xor(s, off, 64);
      v += __shfl_xor(v, off, 64);
    }
    if (lane == 0) wsb[p * 64 + chunk] = make_float2(m + flog2(s), v * frcp(s));
    const float err = tgt[p] - pred;
    c = fmaf(C2 * err, err, c);
  }
}

extern "C" void kernel_launch(void* const* d_in, const int* in_sizes, int n_in,
                              void* d_out, int out_size, void* d_ws, size_t ws_size,
                              hipStream_t stream) {
  const float* data      = (const float*)d_in[0];
  const float* targets   = (const float*)d_in[1];
  const float* task_pool = (const float*)d_in[2];
  float* out = (float*)d_out;

  if (ws_size >= WS_NEED) {
    float2*   trips = (float2*)d_ws;
    char*     cb    = (char*)d_ws + TRIP_BYTES;
    ushort_t* Ah    = (ushort_t*)cb;
    ushort_t* Al    = (ushort_t*)(cb + A_BF_BYTES);
    ushort_t* Bh    = (ushort_t*)(cb + 2 * A_BF_BYTES);
    ushort_t* Bl    = (ushort_t*)(cb + 2 * A_BF_BYTES + B_BF_BYTES);
    k_conv <<<dim3((Bb * Pp * Dd + Tt * Dd) / 256), dim3(256), 0, stream>>>(
        data, task_pool, Ah, Al, Bh, Bl);
    k_main <<<dim3(Bb * 16), dim3(256), 0, stream>>>(Ah, Al, Bh, Bl, targets, trips);
    k_merge<<<dim3((Bb * Pp * 64) / 256), dim3(256), 0, stream>>>(trips, out);
  } else {
    float2* trips = (float2*)d_ws;   // 4.2 MB
    k_scan_fused<<<dim3(512), dim3(256), 0, stream>>>(data, targets, task_pool, trips);
    k_merge<<<dim3((Bb * Pp * 64) / 256), dim3(256), 0, stream>>>(trips, out);
  }
}

// Round 9
// 97.202 us; speedup vs baseline: 1.0345x; 1.0240x over previous
//
#include <hip/hip_runtime.h>
#include <hip/hip_bf16.h>
#include <math.h>

// Problem constants (reference: B=32, P=256, D=64, T=4096, SCALE=1)
#define Bb 32
#define Pp 256
#define Dd 64
#define Tt 4096

typedef unsigned short ushort_t;
typedef __attribute__((ext_vector_type(8))) short bf16x8;   // 8 bf16 = 4 VGPRs
typedef __attribute__((ext_vector_type(4))) float f32x4;

// Partials: 64 per (b,p), packed float2(lm = M + log2(ss), u = vv/ss).
#define TRIP_BYTES ((size_t)Bb * Pp * 64 * 8)    // 4,194,304
#define WS_NEED    TRIP_BYTES

// Log2-domain logits (R14/R16-validated): one v_exp_f32 per exp.
#define C2 (-0.7213475204444817f)   // -0.5 * log2(e)

__device__ __forceinline__ float fexp2(float x) {
  float r; asm("v_exp_f32 %0, %1" : "=v"(r) : "v"(x)); return r;
}
__device__ __forceinline__ float flog2(float x) {
  float r; asm("v_log_f32 %0, %1" : "=v"(r) : "v"(x)); return r;
}
__device__ __forceinline__ float frcp(float x) {
  float r; asm("v_rcp_f32 %0, %1" : "=v"(r) : "v"(x)); return r;
}

// ---- DPP row-local shuffle on the VALU pipe (R13-proven ctrl codes).
// quad_perm xor1 = 0xB1, quad_perm xor2 = 0x4E,
// row_half_mirror = 0x141 (cross-4 merge), row_mirror = 0x140 (cross-8).
template <int CTRL>
__device__ __forceinline__ float dppf(float x) {
  return __builtin_bit_cast(float,
      __builtin_amdgcn_update_dpp(0, __builtin_bit_cast(int, x), CTRL, 0xF, 0xF, true));
}

// R9-proven split-bf16 6-MFMA product (drops al*bl, ~2^-17 rel err)
__device__ __forceinline__ f32x4 mfma6(bf16x8 ah0, bf16x8 ah1, bf16x8 al0, bf16x8 al1,
                                       bf16x8 bh0, bf16x8 bh1, bf16x8 bl0, bf16x8 bl1) {
  f32x4 a = (f32x4)0.f;
  a = __builtin_amdgcn_mfma_f32_16x16x32_bf16(ah0, bh0, a, 0, 0, 0);
  a = __builtin_amdgcn_mfma_f32_16x16x32_bf16(ah1, bh1, a, 0, 0, 0);
  a = __builtin_amdgcn_mfma_f32_16x16x32_bf16(ah0, bl0, a, 0, 0, 0);
  a = __builtin_amdgcn_mfma_f32_16x16x32_bf16(al0, bh0, a, 0, 0, 0);
  a = __builtin_amdgcn_mfma_f32_16x16x32_bf16(ah1, bl1, a, 0, 0, 0);
  a = __builtin_amdgcn_mfma_f32_16x16x32_bf16(al1, bh1, a, 0, 0, 0);
  return a;
}

// ---- In-register split-bf16 of 8 floats. R21: unlike R14's version (float
// f[8] array inside a lambda under a 128-VGPR cap -> scratch), this is
// straight-line with NAMED SCALARS and CONSTANT vector indices only, and the
// kernel runs at (256,2) (256-reg budget). Same RNE hi + RNE residual as the
// old k_conv (numerics identical).
__device__ __forceinline__ void cvt8(const float4 a, const float4 b,
                                     bf16x8& hi, bf16x8& lo) {
#define CVT1(X, IDX)                                          \
  {                                                           \
    const __hip_bfloat16 hb = __float2bfloat16(X);            \
    const float hf = __bfloat162float(hb);                    \
    const __hip_bfloat16 lb = __float2bfloat16((X) - hf);     \
    hi[IDX] = __builtin_bit_cast(short, hb);                  \
    lo[IDX] = __builtin_bit_cast(short, lb);                  \
  }
  CVT1(a.x, 0) CVT1(a.y, 1) CVT1(a.z, 2) CVT1(a.w, 3)
  CVT1(b.x, 4) CVT1(b.y, 5) CVT1(b.z, 6) CVT1(b.w, 7)
#undef CVT1
}

// ==================== Phase 1: one-pass fused prefix-softmax ================
// R21: k_conv FOLDED IN (deletes a 6us kernel + ~2.5us launch gap).
// Rationale: split-bf16 hi+lo is byte-identical to f32, so loading f32 and
// converting in-register adds ZERO HBM traffic; B rows are wave-unique (no
// redundant conversion) and A loads are L1/L2-hot re-reads that happened
// anyway (~50 VALU/sg conversion add-on, partially hidden in the measured
// ~55% stall space). R14's spill was the (256,4) 128-reg cap + array/lambda
// scratch (R15/R16 isolated this); here: (256,2) + array-free cvt8.
// Body = R18 (converged at ~40us: 64 t/wave, 4-nt runs, A-prefetch; R19
// dual-row ILP and R20 software pipeline both failed to beat it).
// Numerics: R18-proven (log2 domain, M-first exact-max softmax, float2(lm,u)
// partials; quad-exclusive prefix scan).
__global__ __launch_bounds__(256, 2) void k_main(const float* __restrict__ data,
                                                 const float* __restrict__ targets,
                                                 const float* __restrict__ task_pool,
                                                 float2* __restrict__ trips) {
  const int tid  = threadIdx.x;
  const int wid  = tid >> 6;
  const int lane = tid & 63;
  const int quad = lane >> 4;
  const int l16  = lane & 15;
  const int b     = blockIdx.x >> 4;
  const int strip = blockIdx.x & 15;
  const int t0    = strip * 256;
  const int wstrip = strip * 4 + wid;           // 0..63 (this wave's t-subset id)

  // ---- B fragments for this wave's 64 t-columns: load f32 (wave-unique
  // rows), convert in-register ONCE, VGPR-resident for all 16 sgs.
  bf16x8 vbh0[4], vbh1[4], vbl0[4], vbl1[4];
#pragma unroll
  for (int nt = 0; nt < 4; ++nt) {
    const float* wr = task_pool + (size_t)(t0 + wid * 64 + nt * 16 + l16) * Dd + quad * 8;
    cvt8(*(const float4*)(wr),      *(const float4*)(wr + 4),  vbh0[nt], vbl0[nt]);
    cvt8(*(const float4*)(wr + 32), *(const float4*)(wr + 36), vbh1[nt], vbl1[nt]);
  }

  const float* arow = data + (size_t)b * Pp * Dd;
  const float* tgt  = targets + b * Pp;
  float2* __restrict__ trb = trips + (size_t)b * Pp * 64;

  float R[4];                                   // per-column running prefix (log2)
#pragma unroll
  for (int nt = 0; nt < 4; ++nt) R[nt] = 0.f;

  // prologue: A fragments (f32 -> split-bf16) + targets for sg=0
  bf16x8 ah0, ah1, al0, al1;
  {
    const float* ar = arow + (size_t)l16 * Dd + quad * 8;
    cvt8(*(const float4*)(ar),      *(const float4*)(ar + 4),  ah0, al0);
    cvt8(*(const float4*)(ar + 32), *(const float4*)(ar + 36), ah1, al1);
  }
  float4 tq = *(const float4*)(tgt + quad * 4);

#pragma unroll 1
  for (int sg = 0; sg < 16; ++sg) {
    // ---- prefetch next sg's A floats early (L1-hot; latency hidden under
    // this sg's compute; converted at the rotation point below)
    const int pn = ((sg + 1) & 15) * 16;
    const float* an = arow + (size_t)(pn + l16) * Dd + quad * 8;
    const float4 nf0 = *(const float4*)(an);
    const float4 nf1 = *(const float4*)(an + 4);
    const float4 nf2 = *(const float4*)(an + 32);
    const float4 nf3 = *(const float4*)(an + 36);
    const float4 ntq = *(const float4*)(tgt + pn + quad * 4);

    float cc[4][4], av[4][4];
#pragma unroll
    for (int nt = 0; nt < 4; ++nt) {
      const f32x4 a = mfma6(ah0, ah1, al0, al1,
                            vbh0[nt], vbh1[nt], vbl0[nt], vbl1[nt]);
      float sc0, sc1, sc2, sc3;
      { const float e = tq.x - a[0]; sc0 = C2 * e * e; }
      { const float e = tq.y - a[1]; sc1 = C2 * e * e; }
      { const float e = tq.z - a[2]; sc2 = C2 * e * e; }
      { const float e = tq.w - a[3]; sc3 = C2 * e * e; }

      // quad-exclusive prefix of column sums (R11-proven; cross-row -> DS)
      const float colsum = (sc0 + sc1) + (sc2 + sc3);
      const float x1 = __shfl_xor(colsum, 16, 64);
      const float x2 = __shfl_xor(colsum, 32, 64);
      const float x3 = __shfl_xor(x1, 32, 64);
      const float pre = (quad == 0) ? 0.f
                      : (quad == 1) ? x1
                      : (quad == 2) ? (x2 + x3)
                                    : (x1 + x2 + x3);
      const float base = R[nt] + pre;
      cc[nt][0] = base;
      cc[nt][1] = base + sc0;
      cc[nt][2] = cc[nt][1] + sc1;
      cc[nt][3] = cc[nt][2] + sc2;
      av[nt][0] = a[0]; av[nt][1] = a[1]; av[nt][2] = a[2]; av[nt][3] = a[3];
      R[nt] += ((colsum + x1) + (x2 + x3));     // inclusive through this sg
    }

    // ---- M-first softmax: exact max over 64 t (in-lane 4 + DPP butterfly)
    float M[4];
#pragma unroll
    for (int r = 0; r < 4; ++r)
      M[r] = fmaxf(fmaxf(cc[0][r], cc[1][r]), fmaxf(cc[2][r], cc[3][r]));
#pragma unroll
    for (int r = 0; r < 4; ++r) M[r] = fmaxf(M[r], dppf<0xB1>(M[r]));   // xor1
#pragma unroll
    for (int r = 0; r < 4; ++r) M[r] = fmaxf(M[r], dppf<0x4E>(M[r]));   // xor2
#pragma unroll
    for (int r = 0; r < 4; ++r) M[r] = fmaxf(M[r], dppf<0x141>(M[r]));  // cross-4
#pragma unroll
    for (int r = 0; r < 4; ++r) M[r] = fmaxf(M[r], dppf<0x140>(M[r]));  // cross-8

    // single exp2 per column against the exact max (argmax term == 1)
    float ss[4], vv[4];
#pragma unroll
    for (int r = 0; r < 4; ++r) {
      float s = 0.f, v = 0.f;
#pragma unroll
      for (int nt = 0; nt < 4; ++nt) {
        const float e = fexp2(cc[nt][r] - M[r]);
        s += e;
        v = fmaf(e, av[nt][r], v);
      }
      ss[r] = s; vv[r] = v;
    }

#pragma unroll
    for (int r = 0; r < 4; ++r) { ss[r] += dppf<0xB1>(ss[r]);  vv[r] += dppf<0xB1>(vv[r]); }
#pragma unroll
    for (int r = 0; r < 4; ++r) { ss[r] += dppf<0x4E>(ss[r]);  vv[r] += dppf<0x4E>(vv[r]); }
#pragma unroll
    for (int r = 0; r < 4; ++r) { ss[r] += dppf<0x141>(ss[r]); vv[r] += dppf<0x141>(vv[r]); }
#pragma unroll
    for (int r = 0; r < 4; ++r) { ss[r] += dppf<0x140>(ss[r]); vv[r] += dppf<0x140>(vv[r]); }

    if (l16 == 0) {
#pragma unroll
      for (int r = 0; r < 4; ++r) {
        const float lm = M[r] + flog2(ss[r]);   // ss >= 1 -> log2 safe
        const float u  = vv[r] * frcp(ss[r]);
        const int p = sg * 16 + quad * 4 + r;
        trb[p * 64 + wstrip] = make_float2(lm, u);
      }
    }

    // rotate: convert prefetched A floats for next sg (short VALU tail;
    // the loads themselves were issued at loop top, latency already hidden)
    cvt8(nf0, nf1, ah0, al0);
    cvt8(nf2, nf3, ah1, al1);
    tq = ntq;
  }
}

// ==================== Phase 2: cross-strip merge (separate, parallel) =======
// R18-proven: one 64-lane wave per (b,p) row, 2048-wave parallelism. (R17's
// fused last-block merge was a 78us serial tail at 1.5% occupancy — never
// fuse this.)
__global__ __launch_bounds__(256) void k_merge(const float2* __restrict__ ws,
                                               float* __restrict__ out) {
  const int gt   = blockIdx.x * 256 + threadIdx.x;
  const int bp   = gt >> 6;
  const int lane = gt & 63;
  const float2 e = ws[(size_t)bp * 64 + lane];
  float M = e.x;
#pragma unroll
  for (int off = 32; off; off >>= 1) M = fmaxf(M, __shfl_xor(M, off, 64));
  const float f = fexp2(e.x - M);
  float S = f, V = f * e.y;
#pragma unroll
  for (int off = 32; off; off >>= 1) {
    S += __shfl_xor(S, off, 64);
    V += __shfl_xor(V, off, 64);
  }
  if (lane == 0) out[bp] = V / S;
}

// ============== Fallback (tiny ws): fused R1 structure + merge ==============
__global__ __launch_bounds__(256) void k_scan_fused(const float* __restrict__ data,
                                                    const float* __restrict__ targets,
                                                    const float* __restrict__ task_pool,
                                                    float2* __restrict__ ws) {
  const int b     = blockIdx.x >> 4;
  const int wid   = threadIdx.x >> 6;
  const int lane  = threadIdx.x & 63;
  const int chunk = ((blockIdx.x & 15) << 2) | wid;
  const int t     = (chunk << 6) | lane;
  float w[Dd];
#pragma unroll
  for (int d = 0; d < Dd; d += 4) {
    const float4 r = *(const float4*)(task_pool + (size_t)t * Dd + d);
    w[d] = r.x; w[d + 1] = r.y; w[d + 2] = r.z; w[d + 3] = r.w;
  }
  const float* drow = data + (size_t)b * (Pp * Dd);
  const float* tgt  = targets + b * Pp;
  float2* wsb       = ws + (size_t)b * (Pp * 64);
  float c = 0.f;
  for (int p = 0; p < Pp; ++p) {
    float a0 = 0.f, a1 = 0.f, a2 = 0.f, a3 = 0.f;
    const float* r = drow + p * Dd;
#pragma unroll
    for (int d = 0; d < Dd; d += 4) {
      a0 = fmaf(r[d], w[d], a0);         a1 = fmaf(r[d + 1], w[d + 1], a1);
      a2 = fmaf(r[d + 2], w[d + 2], a2); a3 = fmaf(r[d + 3], w[d + 3], a3);
    }
    const float pred = (a0 + a1) + (a2 + a3);
    float m = c;
#pragma unroll
    for (int off = 32; off; off >>= 1) m = fmaxf(m, __shfl_xor(m, off, 64));
    const float e = fexp2(c - m);
    float s = e, v = e * pred;
#pragma unroll
    for (int off = 32; off; off >>= 1) {
      s += __shfl_xor(s, off, 64);
      v += __shfl_xor(v, off, 64);
    }
    if (lane == 0) wsb[p * 64 + chunk] = make_float2(m + flog2(s), v * frcp(s));
    const float err = tgt[p] - pred;
    c = fmaf(C2 * err, err, c);
  }
}

extern "C" void kernel_launch(void* const* d_in, const int* in_sizes, int n_in,
                              void* d_out, int out_size, void* d_ws, size_t ws_size,
                              hipStream_t stream) {
  const float* data      = (const float*)d_in[0];
  const float* targets   = (const float*)d_in[1];
  const float* task_pool = (const float*)d_in[2];
  float* out = (float*)d_out;

  float2* trips = (float2*)d_ws;   // 4.2 MB
  if (ws_size >= WS_NEED) {
    k_main <<<dim3(Bb * 16), dim3(256), 0, stream>>>(data, targets, task_pool, trips);
    k_merge<<<dim3((Bb * Pp * 64) / 256), dim3(256), 0, stream>>>(trips, out);
  } else {
    k_scan_fused<<<dim3(512), dim3(256), 0, stream>>>(data, targets, task_pool, trips);
    k_merge<<<dim3((Bb * Pp * 64) / 256), dim3(256), 0, stream>>>(trips, out);
  }
}